// Round 7
// baseline (386.836 us; speedup 1.0000x reference)
//
#include <hip/hip_runtime.h>

using half2v  = __attribute__((ext_vector_type(2))) _Float16;
using half4   = __attribute__((ext_vector_type(4))) _Float16;
using half8   = __attribute__((ext_vector_type(8))) _Float16;
using floatx4 = __attribute__((ext_vector_type(4))) float;

constexpr int BATCH = 2;
constexpr int NPOS  = 96 * 96;    // 9216
constexpr int NT    = NPOS / 16;  // 576 sixteen-wide i-tiles
constexpr int NST   = NPOS / 32;  // 288 thirty-two-wide j-steps
constexpr int GRID  = 768;        // exactly 3 blocks/CU on 256 CUs

#define EXP2(x) __builtin_amdgcn_exp2f(x)

__device__ inline half8 p8_of(floatx4 e0, floatx4 e1) {
    half2v a0 = __builtin_bit_cast(half2v,
        __builtin_amdgcn_cvt_pkrtz(EXP2(e0[0]), EXP2(e0[1])));
    half2v a1 = __builtin_bit_cast(half2v,
        __builtin_amdgcn_cvt_pkrtz(EXP2(e0[2]), EXP2(e0[3])));
    half2v a2 = __builtin_bit_cast(half2v,
        __builtin_amdgcn_cvt_pkrtz(EXP2(e1[0]), EXP2(e1[1])));
    half2v a3 = __builtin_bit_cast(half2v,
        __builtin_amdgcn_cvt_pkrtz(EXP2(e1[2]), EXP2(e1[3])));
    half8 p = {a0[0], a0[1], a1[0], a1[1], a2[0], a2[1], a3[0], a3[1]};
    return p;
}

// Device-scope barrier: all GRID blocks are co-resident by construction
// (LDS pinned to 3 blocks/CU, VGPR <= 128 via launch_bounds(256,4)).
// Agent-scope atomics emit the cross-XCD L2 writeback/invalidate.
__device__ inline void gbar(unsigned* bar, int slot) {
    __syncthreads();
    if (threadIdx.x == 0) {
        __threadfence();
        __hip_atomic_fetch_add(bar + slot, 1u,
                               __ATOMIC_ACQ_REL, __HIP_MEMORY_SCOPE_AGENT);
        while (__hip_atomic_load(bar + slot,
                                 __ATOMIC_ACQUIRE, __HIP_MEMORY_SCOPE_AGENT)
               < (unsigned)GRID)
            __builtin_amdgcn_s_sleep(8);
    }
    __syncthreads();
}

// ---------------------------------------------------------------------------
// Fused persistent kernel: phase 0 qkv -> phase 1 denom -> phase 2 patch ->
// phase 3 attention (all R6-proven bodies), one dispatch, 3 global barriers.
// LDS: 43.5 KB union (also pins occupancy to exactly 3 blocks/CU).
// ---------------------------------------------------------------------------
__global__ __launch_bounds__(256, 4) void fused_kernel(
    const float* __restrict__ x,
    const float* __restrict__ wq, const float* __restrict__ bq,
    const float* __restrict__ wk, const float* __restrict__ bk,
    const float* __restrict__ wv, const float* __restrict__ bv,
    const float* __restrict__ gamma,
    _Float16* __restrict__ Qf, _Float16* __restrict__ Kf,
    _Float16* __restrict__ Vf, float* __restrict__ Lp,
    unsigned* __restrict__ bar, float* __restrict__ out)
{
    __shared__ __align__(16) char smem[44032];   // > 40 KB => max 3 blocks/CU
    const int bi  = blockIdx.x;
    const int tid = threadIdx.x;

    // ======================= phase 0: QKV projection =======================
    if (bi < 576) {
        float (*W)[64]      = (float (*)[64])smem;              // 20480
        float* bias         = (float*)(smem + 20480);           // 320
        float (*qs)[8]      = (float (*)[8])(smem + 20800);     // 1024
        float (*ks)[8]      = (float (*)[8])(smem + 21824);     // 1024
        _Float16 (*vs)[64]  = (_Float16 (*)[64])(smem + 22848); // 4096

        for (int idx = tid; idx < 80 * 64; idx += 256) {
            int o = idx >> 6, c = idx & 63;
            float w;
            if (o < 8)       w = wq[o * 64 + c];
            else if (o < 16) w = wk[(o - 8) * 64 + c];
            else             w = wv[(o - 16) * 64 + c];
            W[o][c] = w;
        }
        if (tid < 80) {
            float bb;
            if (tid < 8)       bb = bq[tid];
            else if (tid < 16) bb = bk[tid - 8];
            else               bb = bv[tid - 16];
            bias[tid] = bb;
        }
        __syncthreads();

        const int js = bi % NST;
        const int b  = bi / NST;
        const int part = tid >> 5;          // 0..7
        const int jl   = tid & 31;
        const int i    = js * 32 + jl;

        float xr[64];
        #pragma unroll
        for (int c = 0; c < 64; ++c)
            xr[c] = x[(size_t)(b * 64 + c) * NPOS + i];

        #pragma unroll
        for (int q = 0; q < 10; ++q) {
            const int o = part * 10 + q;
            float s = bias[o];
            #pragma unroll
            for (int c4 = 0; c4 < 16; ++c4) {
                float4 w4 = *(const float4*)&W[o][c4 * 4];
                s += w4.x * xr[c4*4+0] + w4.y * xr[c4*4+1]
                   + w4.z * xr[c4*4+2] + w4.w * xr[c4*4+3];
            }
            if (o < 8)       qs[jl][o] = s;
            else if (o < 16) ks[jl][o - 8] = s;
            else             vs[jl][o - 16] = (_Float16)s;
        }
        __syncthreads();

        const size_t tile = (size_t)b * NST + js;
        {   // Vf
            const int ct = tid >> 6, l = tid & 63;
            const int g = l >> 4, cl = l & 15;
            half8 o8;
            #pragma unroll
            for (int idx = 0; idx < 8; ++idx)
                o8[idx] = vs[8 * g + idx][16 * ct + cl];
            *(half8*)&Vf[(tile * 256 + ct * 64 + l) * 8] = o8;
        }
        if (tid < 128) {   // Qf (j-permuted, log2e-scaled)
            const int l = tid >> 1, e = tid & 1;
            const int m = l & 15, g = l >> 4;
            const int jsrc = 8 * (m >> 2) + 4 * e + (m & 3);
            constexpr float LOG2E = 1.44269504088896f;
            half4 qh;
            #pragma unroll
            for (int r = 0; r < 4; ++r)
                qh[r] = (g < 2) ? (_Float16)(qs[jsrc][4 * g + r] * LOG2E)
                                : (_Float16)0.f;
            ((half4*)Qf)[(tile * 64 + l) * 2 + e] = qh;
        } else {           // Kf (augment dims d=8,9 -> 1.0)
            const int t = tid - 128;
            const int ht = t >> 6, l = t & 63;
            const int il = l & 15, g = l >> 4;
            const int it = js * 2 + ht;
            half4 kh;
            #pragma unroll
            for (int r = 0; r < 4; ++r) {
                if (g < 2)       kh[r] = (_Float16)ks[16 * ht + il][4 * g + r];
                else if (g == 2) kh[r] = (r < 2) ? (_Float16)1.f : (_Float16)0.f;
                else             kh[r] = (_Float16)0.f;
            }
            ((half4*)Kf)[(size_t)(b * NT + it) * 64 + l] = kh;
        }
    }
    gbar(bar, 0);

    // ======================= phase 1: denominators =========================
    if (bi < 576) {
        float (*LpS)[64] = (float (*)[64])smem;
        const int w = tid >> 6, l = tid & 63;
        const int jgl = bi % 144;
        const int rem = bi / 144;
        const int b   = rem & 1;
        const int ih  = rem >> 1;
        const half8* __restrict__ qfb = (const half8*)Qf + (size_t)b * NST * 64;
        const half4* __restrict__ kfb = (const half4*)Kf + (size_t)b * NT * 64;

        half8 qvA = qfb[(size_t)(jgl * 2 + 0) * 64 + l];
        half8 qvB = qfb[(size_t)(jgl * 2 + 1) * 64 + l];
        half4 q0 = __builtin_shufflevector(qvA, qvA, 0, 1, 2, 3);
        half4 q1 = __builtin_shufflevector(qvA, qvA, 4, 5, 6, 7);
        half4 q2 = __builtin_shufflevector(qvB, qvB, 0, 1, 2, 3);
        half4 q3 = __builtin_shufflevector(qvB, qvB, 4, 5, 6, 7);

        float sum[4][4];
        #pragma unroll
        for (int s = 0; s < 4; ++s)
            #pragma unroll
            for (int r = 0; r < 4; ++r) sum[s][r] = 0.f;

        #define DSTEP(KF) do { \
            floatx4 z = {0.f,0.f,0.f,0.f}; \
            floatx4 e0 = __builtin_amdgcn_mfma_f32_16x16x16f16(q0, KF, z, 0,0,0); \
            floatx4 e1 = __builtin_amdgcn_mfma_f32_16x16x16f16(q1, KF, z, 0,0,0); \
            floatx4 e2 = __builtin_amdgcn_mfma_f32_16x16x16f16(q2, KF, z, 0,0,0); \
            floatx4 e3 = __builtin_amdgcn_mfma_f32_16x16x16f16(q3, KF, z, 0,0,0); \
            _Pragma("unroll") \
            for (int r = 0; r < 4; ++r) { \
                sum[0][r] += EXP2(e0[r]); sum[1][r] += EXP2(e1[r]); \
                sum[2][r] += EXP2(e2[r]); sum[3][r] += EXP2(e3[r]); } \
        } while (0)

        const half4* kp = kfb + (size_t)(ih * (NT/2) + w) * 64 + l;
        half4 kf = *kp;
        for (int k = 0; k < 71; ++k) {
            kp += 256;
            half4 kn = *kp;
            DSTEP(kf);
            kf = kn;
        }
        DSTEP(kf);
        #undef DSTEP

        #pragma unroll
        for (int s = 0; s < 4; ++s)
            #pragma unroll
            for (int r = 0; r < 4; ++r)
                #pragma unroll
                for (int m = 1; m < 16; m <<= 1)
                    sum[s][r] += __shfl_xor(sum[s][r], m, 64);

        if ((l & 15) == 0) {
            const int g = l >> 4;
            #pragma unroll
            for (int s = 0; s < 4; ++s)
                #pragma unroll
                for (int r = 0; r < 4; ++r)
                    LpS[w][(s >> 1) * 32 + 8 * g + 4 * (s & 1) + r] = sum[s][r];
        }
        __syncthreads();
        if (tid < 64) {
            float tot = LpS[0][tid] + LpS[1][tid] + LpS[2][tid] + LpS[3][tid];
            Lp[((size_t)ih * BATCH + b) * NPOS + jgl * 64 + tid] = tot;
        }
    }
    gbar(bar, 1);

    // ======================= phase 2: patch Qf augment =====================
    if (bi < 72) {
        const int idx = bi * 256 + tid;         // 0 .. 18431
        const int b = idx / NPOS;
        const int j = idx - b * NPOS;
        const float L = Lp[(size_t)b * NPOS + j]
                      + Lp[(size_t)(BATCH + b) * NPOS + j];
        const float v = -__log2f(L);
        _Float16 hi = (_Float16)v;
        _Float16 lo = (_Float16)(v - (float)hi);
        const int js = j >> 5, off = j & 31;
        const int m = ((off >> 3) << 2) | (off & 3);
        const int e = (off >> 2) & 1;
        const size_t tile = (size_t)b * NST + js;
        half2v hl = {hi, lo};
        ((half2v*)Qf)[((tile * 64 + m + 32) * 2 + e) * 2] = hl;
    }
    gbar(bar, 2);

    // ======================= phase 3: attention ============================
    {
        float (*red)[3][64][9] = (float (*)[3][64][9])smem;
        const int s = bi;
        const int xcd = s & 7;
        const int b   = xcd >> 2;
        const int r2  = (s >> 3) * 4 + (xcd & 3);   // 0..383
        const int igl = r2 % 192;
        const int ch  = r2 / 192;
        const int w = tid >> 6, l = tid & 63;
        const int it0 = igl * 3, i0 = igl * 48;

        const half8* __restrict__ qfb = (const half8*)Qf + (size_t)b * NST * 64;
        const half4* __restrict__ kfb = (const half4*)Kf + (size_t)b * NT * 64;
        const half8* __restrict__ vfb = (const half8*)Vf + (size_t)b * NST * 256;

        half4 kf[3];
        #pragma unroll
        for (int st = 0; st < 3; ++st) kf[st] = kfb[(size_t)(it0 + st) * 64 + l];

        floatx4 acc[3][2];
        #pragma unroll
        for (int st = 0; st < 3; ++st) {
            acc[st][0] = (floatx4){0.f, 0.f, 0.f, 0.f};
            acc[st][1] = (floatx4){0.f, 0.f, 0.f, 0.f};
        }

        #define ASTEP(QV, V0, V1) do { \
            half4 qe0 = __builtin_shufflevector(QV, QV, 0, 1, 2, 3); \
            half4 qe1 = __builtin_shufflevector(QV, QV, 4, 5, 6, 7); \
            floatx4 z = {0.f,0.f,0.f,0.f}; \
            _Pragma("unroll") \
            for (int st = 0; st < 3; ++st) { \
                floatx4 e0 = __builtin_amdgcn_mfma_f32_16x16x16f16(qe0, kf[st], z, 0,0,0); \
                floatx4 e1 = __builtin_amdgcn_mfma_f32_16x16x16f16(qe1, kf[st], z, 0,0,0); \
                half8 p = p8_of(e0, e1); \
                acc[st][0] = __builtin_amdgcn_mfma_f32_16x16x32_f16(V0, p, acc[st][0], 0,0,0); \
                acc[st][1] = __builtin_amdgcn_mfma_f32_16x16x32_f16(V1, p, acc[st][1], 0,0,0); \
            } \
        } while (0)

        const half8* qp = qfb + (size_t)w * 64 + l;
        const half8* vp = vfb + (size_t)w * 256 + ch * 128 + l;
        half8 qv = *qp;
        half8 v0 = vp[0], v1 = vp[64];
        for (int k = 0; k < 71; ++k) {
            qp += 256; vp += 1024;
            half8 qn  = *qp;
            half8 v0n = vp[0], v1n = vp[64];
            ASTEP(qv, v0, v1);
            qv = qn; v0 = v0n; v1 = v1n;
        }
        ASTEP(qv, v0, v1);
        #undef ASTEP

        #pragma unroll
        for (int st = 0; st < 3; ++st)
            #pragma unroll
            for (int t2 = 0; t2 < 2; ++t2)
                #pragma unroll
                for (int r = 0; r < 4; ++r)
                    red[w][st][l][t2 * 4 + r] = acc[st][t2][r];
        __syncthreads();

        if (w < 3) {
            const float g = gamma[0];
            const int iq = i0 + 16 * w + (l & 15);
            #pragma unroll
            for (int t2 = 0; t2 < 2; ++t2)
                #pragma unroll
                for (int r = 0; r < 4; ++r) {
                    float v = red[0][w][l][t2*4+r] + red[1][w][l][t2*4+r]
                            + red[2][w][l][t2*4+r] + red[3][w][l][t2*4+r];
                    int c = 16 * (2 * ch + t2) + 4 * (l >> 4) + r;
                    size_t o = ((size_t)(b * 64 + c)) * NPOS + iq;
                    out[o] = g * v + x[o];
                }
        }
    }
}

// ---------------------------------------------------------------------------
extern "C" void kernel_launch(void* const* d_in, const int* in_sizes, int n_in,
                              void* d_out, int out_size, void* d_ws, size_t ws_size,
                              hipStream_t stream)
{
    const float* x     = (const float*)d_in[0];
    const float* wq    = (const float*)d_in[1];
    const float* bq    = (const float*)d_in[2];
    const float* wk    = (const float*)d_in[3];
    const float* bk    = (const float*)d_in[4];
    const float* wv    = (const float*)d_in[5];
    const float* bv    = (const float*)d_in[6];
    const float* gamma = (const float*)d_in[7];
    float* out = (float*)d_out;

    char* wsb = (char*)d_ws;
    _Float16* Qf  = (_Float16*)wsb;                      //   589,824 B
    _Float16* Kf  = (_Float16*)(wsb + 589824);           //   589,824 B
    _Float16* Vf  = (_Float16*)(wsb + 1179648);          // 2,359,296 B
    float*    Lp  = (float*)(wsb + 3538944);             //   147,456 B
    unsigned* bar = (unsigned*)(wsb + 3686400);          //       128 B

    hipMemsetAsync(bar, 0, 128, stream);

    fused_kernel<<<dim3(GRID), 256, 0, stream>>>(
        x, wq, bq, wk, bk, wv, bv, gamma, Qf, Kf, Vf, Lp, bar, out);
}

// Round 8
// 144.802 us; speedup vs baseline: 2.6715x; 2.6715x over previous
//
#include <hip/hip_runtime.h>

using half2v  = __attribute__((ext_vector_type(2))) _Float16;
using half4   = __attribute__((ext_vector_type(4))) _Float16;
using half8   = __attribute__((ext_vector_type(8))) _Float16;
using floatx4 = __attribute__((ext_vector_type(4))) float;

constexpr int BATCH = 2;
constexpr int NPOS  = 96 * 96;    // 9216
constexpr int NT    = NPOS / 16;  // 576 sixteen-wide i-tiles
constexpr int NST   = NPOS / 32;  // 288 thirty-two-wide j-steps

#define EXP2(x) __builtin_amdgcn_exp2f(x)
#define MFMA16(A, B, C) __builtin_amdgcn_mfma_f32_16x16x16f16(A, B, C, 0, 0, 0)
#define MFMA32(A, B, C) __builtin_amdgcn_mfma_f32_16x16x32_f16(A, B, C, 0, 0, 0)

__device__ inline half8 p8_of(floatx4 e0, floatx4 e1) {
    half2v a0 = __builtin_bit_cast(half2v,
        __builtin_amdgcn_cvt_pkrtz(EXP2(e0[0]), EXP2(e0[1])));
    half2v a1 = __builtin_bit_cast(half2v,
        __builtin_amdgcn_cvt_pkrtz(EXP2(e0[2]), EXP2(e0[3])));
    half2v a2 = __builtin_bit_cast(half2v,
        __builtin_amdgcn_cvt_pkrtz(EXP2(e1[0]), EXP2(e1[1])));
    half2v a3 = __builtin_bit_cast(half2v,
        __builtin_amdgcn_cvt_pkrtz(EXP2(e1[2]), EXP2(e1[3])));
    half8 p = {a0[0], a0[1], a1[0], a1[1], a2[0], a2[1], a3[0], a3[1]};
    return p;
}

// ---------------------------------------------------------------------------
// K1: QKV projection (R6 body, LDS padded to kill bank conflicts).
// Qf: j-permuted A-layout, log2e-scaled, d>=8 zeroed (denom runs pre-patch).
// Kf: B-layout, d=8,9 = 1.0 (augment channels). Vf: K=32 A-layout f16.
// ---------------------------------------------------------------------------
__global__ __launch_bounds__(256) void qkv_kernel(
    const float* __restrict__ x,
    const float* __restrict__ wq, const float* __restrict__ bq,
    const float* __restrict__ wk, const float* __restrict__ bk,
    const float* __restrict__ wv, const float* __restrict__ bv,
    _Float16* __restrict__ Qf, _Float16* __restrict__ Kf,
    _Float16* __restrict__ Vf)
{
    __shared__ float W[80][64];
    __shared__ float bias[80];
    __shared__ float qs[32][9];
    __shared__ float ks[32][9];
    __shared__ _Float16 vs[32][72];
    const int tid = threadIdx.x;
    for (int idx = tid; idx < 80 * 64; idx += 256) {
        int o = idx >> 6, c = idx & 63;
        float w;
        if (o < 8)       w = wq[o * 64 + c];
        else if (o < 16) w = wk[(o - 8) * 64 + c];
        else             w = wv[(o - 16) * 64 + c];
        W[o][c] = w;
    }
    if (tid < 80) {
        float bb;
        if (tid < 8)       bb = bq[tid];
        else if (tid < 16) bb = bk[tid - 8];
        else               bb = bv[tid - 16];
        bias[tid] = bb;
    }
    __syncthreads();

    const int js = blockIdx.x;          // 0..287
    const int b  = blockIdx.y;
    const int part = tid >> 5;          // 0..7
    const int jl   = tid & 31;
    const int i    = js * 32 + jl;

    float xr[64];
    #pragma unroll
    for (int c = 0; c < 64; ++c)
        xr[c] = x[(size_t)(b * 64 + c) * NPOS + i];

    #pragma unroll
    for (int q = 0; q < 10; ++q) {
        const int o = part * 10 + q;
        float s = bias[o];
        #pragma unroll
        for (int c4 = 0; c4 < 16; ++c4) {
            float4 w4 = *(const float4*)&W[o][c4 * 4];
            s += w4.x * xr[c4*4+0] + w4.y * xr[c4*4+1]
               + w4.z * xr[c4*4+2] + w4.w * xr[c4*4+3];
        }
        if (o < 8)       qs[jl][o] = s;
        else if (o < 16) ks[jl][o - 8] = s;
        else             vs[jl][o - 16] = (_Float16)s;
    }
    __syncthreads();

    const size_t tile = (size_t)b * NST + js;
    {   // Vf
        const int ct = tid >> 6, l = tid & 63;
        const int g = l >> 4, cl = l & 15;
        half8 o8;
        #pragma unroll
        for (int idx = 0; idx < 8; ++idx)
            o8[idx] = vs[8 * g + idx][16 * ct + cl];
        *(half8*)&Vf[(tile * 256 + ct * 64 + l) * 8] = o8;
    }
    if (tid < 128) {   // Qf (j-permuted, log2e-scaled)
        const int l = tid >> 1, e = tid & 1;
        const int m = l & 15, g = l >> 4;
        const int jsrc = 8 * (m >> 2) + 4 * e + (m & 3);
        constexpr float LOG2E = 1.44269504088896f;
        half4 qh;
        #pragma unroll
        for (int r = 0; r < 4; ++r)
            qh[r] = (g < 2) ? (_Float16)(qs[jsrc][4 * g + r] * LOG2E)
                            : (_Float16)0.f;
        ((half4*)Qf)[(tile * 64 + l) * 2 + e] = qh;
    } else {           // Kf (augment dims d=8,9 -> 1.0)
        const int t = tid - 128;
        const int ht = t >> 6, l = t & 63;
        const int il = l & 15, g = l >> 4;
        const int it = js * 2 + ht;
        half4 kh;
        #pragma unroll
        for (int r = 0; r < 4; ++r) {
            if (g < 2)       kh[r] = (_Float16)ks[16 * ht + il][4 * g + r];
            else if (g == 2) kh[r] = (r < 2) ? (_Float16)1.f : (_Float16)0.f;
            else             kh[r] = (_Float16)0.f;
        }
        ((half4*)Kf)[(size_t)(b * NT + it) * 64 + l] = kh;
    }
}

// ---------------------------------------------------------------------------
// K2: denom + patch fused. Block = ONE 32-j tile x FULL i (grid 288x2).
// Wave w sums i-tiles {w, w+4, ...} (144 steps, e-ping-pong pipelined).
// Epilogue: 4-wave LDS combine -> L, then patch Qf[d=8,9] = hi/lo(-log2 L)
// directly (block owns its j-tile; attn is a later dispatch). No Lp buffer.
// ---------------------------------------------------------------------------
__global__ __launch_bounds__(256, 4) void denom_kernel(
    _Float16* __restrict__ Qf, const _Float16* __restrict__ Kf)
{
    __shared__ float LpS[4][32];
    const int tid = threadIdx.x;
    const int w = tid >> 6, l = tid & 63;
    const int js = blockIdx.x;          // 0..287
    const int b  = blockIdx.y;
    const size_t tile = (size_t)b * NST + js;
    const half8* __restrict__ qfb = (const half8*)Qf + (size_t)b * NST * 64;
    const half4* __restrict__ kfb = (const half4*)Kf + (size_t)b * NT * 64;

    half8 qv = qfb[tile % ((size_t)NST) * 64 + ((size_t)0) + js * 0 + (size_t)js * 64 - (size_t)js * 64 + (size_t)js * 64 + l];
    // (simplified below; kept single clean load)
    qv = qfb[(size_t)js * 64 + l];
    half4 q0 = __builtin_shufflevector(qv, qv, 0, 1, 2, 3);
    half4 q1 = __builtin_shufflevector(qv, qv, 4, 5, 6, 7);

    float sum[2][4];
    #pragma unroll
    for (int e = 0; e < 2; ++e)
        #pragma unroll
        for (int r = 0; r < 4; ++r) sum[e][r] = 0.f;

    const floatx4 z = {0.f, 0.f, 0.f, 0.f};
    #define DACC(E0, E1) do { \
        _Pragma("unroll") \
        for (int r = 0; r < 4; ++r) { \
            sum[0][r] += EXP2(E0[r]); sum[1][r] += EXP2(E1[r]); } \
    } while (0)

    // wave w covers i-tiles it = w + 4k, k = 0..143 (steps in A/B pairs)
    const half4* kp = kfb + (size_t)w * 64 + l;
    half4 kfA = kp[0];
    half4 kfB = kp[256];
    floatx4 eA0 = MFMA16(q0, kfA, z), eA1 = MFMA16(q1, kfA, z);
    floatx4 eB0, eB1;
    for (int k = 0; k < 71; ++k) {
        kfA = kp[(size_t)(2 * k + 2) * 256];
        eB0 = MFMA16(q0, kfB, z); eB1 = MFMA16(q1, kfB, z);
        DACC(eA0, eA1);
        kfB = kp[(size_t)(2 * k + 3) * 256];
        eA0 = MFMA16(q0, kfA, z); eA1 = MFMA16(q1, kfA, z);
        DACC(eB0, eB1);
    }
    eB0 = MFMA16(q0, kfB, z); eB1 = MFMA16(q1, kfB, z);
    DACC(eA0, eA1);
    DACC(eB0, eB1);
    #undef DACC

    // reduce the 16 i-columns (lanes l&15)
    #pragma unroll
    for (int e = 0; e < 2; ++e)
        #pragma unroll
        for (int r = 0; r < 4; ++r)
            #pragma unroll
            for (int m = 1; m < 16; m <<= 1)
                sum[e][r] += __shfl_xor(sum[e][r], m, 64);

    if ((l & 15) == 0) {
        const int g = l >> 4;
        #pragma unroll
        for (int e = 0; e < 2; ++e)
            #pragma unroll
            for (int r = 0; r < 4; ++r)
                LpS[w][8 * g + 4 * e + r] = sum[e][r];
    }
    __syncthreads();

    if (tid < 32) {
        const float L = LpS[0][tid] + LpS[1][tid] + LpS[2][tid] + LpS[3][tid];
        const float v = -__log2f(L);
        _Float16 hi = (_Float16)v;
        _Float16 lo = (_Float16)(v - (float)hi);
        const int m = 4 * (tid >> 3) + (tid & 3);
        const int e = (tid >> 2) & 1;
        half2v hl = {hi, lo};
        ((half2v*)Qf)[((tile * 64 + m + 32) * 2 + e) * 2] = hl;
    }
}

// ---------------------------------------------------------------------------
// K3: attention, direct-out, software-pipelined. Grid 768 (3 blocks/CU),
// block = 48 i x 32 c (c-half) x full j, waves = j-quarters (72 steps).
// Pipeline: eA/eB double-buffer so E-MFMAs(k+1) overlap exp/PV(k); Q/V frags
// 2-deep. Epilogue: 4-wave LDS combine, out = gamma*acc + x.
// ---------------------------------------------------------------------------
__global__ __launch_bounds__(256, 3) void attn_kernel(
    const _Float16* __restrict__ Qf, const _Float16* __restrict__ Kf,
    const _Float16* __restrict__ Vf,
    const float* __restrict__ x, const float* __restrict__ gamma,
    float* __restrict__ out)
{
    __shared__ float red[4][3][64][9];
    const int s = blockIdx.x;
    const int xcd = s & 7;
    const int b   = xcd >> 2;
    const int r2  = (s >> 3) * 4 + (xcd & 3);   // 0..383
    const int igl = r2 % 192;
    const int ch  = r2 / 192;
    const int tid = threadIdx.x;
    const int w = tid >> 6, l = tid & 63;
    const int it0 = igl * 3, i0 = igl * 48;

    const half8* __restrict__ qfb = (const half8*)Qf + (size_t)b * NST * 64;
    const half4* __restrict__ kfb = (const half4*)Kf + (size_t)b * NT * 64;
    const half8* __restrict__ vfb = (const half8*)Vf + (size_t)b * NST * 256;

    half4 kf[3];
    #pragma unroll
    for (int st = 0; st < 3; ++st) kf[st] = kfb[(size_t)(it0 + st) * 64 + l];

    floatx4 acc[3][2];
    #pragma unroll
    for (int st = 0; st < 3; ++st) {
        acc[st][0] = (floatx4){0.f, 0.f, 0.f, 0.f};
        acc[st][1] = (floatx4){0.f, 0.f, 0.f, 0.f};
    }

    const floatx4 z = {0.f, 0.f, 0.f, 0.f};

    #define E_STEP(QV, E) do { \
        half4 qe0 = __builtin_shufflevector(QV, QV, 0, 1, 2, 3); \
        half4 qe1 = __builtin_shufflevector(QV, QV, 4, 5, 6, 7); \
        E[0] = MFMA16(qe0, kf[0], z); E[1] = MFMA16(qe1, kf[0], z); \
        E[2] = MFMA16(qe0, kf[1], z); E[3] = MFMA16(qe1, kf[1], z); \
        E[4] = MFMA16(qe0, kf[2], z); E[5] = MFMA16(qe1, kf[2], z); \
    } while (0)

    #define PXV(E, V0, V1) do { \
        half8 p0 = p8_of(E[0], E[1]); \
        half8 p1 = p8_of(E[2], E[3]); \
        half8 p2 = p8_of(E[4], E[5]); \
        acc[0][0] = MFMA32(V0, p0, acc[0][0]); \
        acc[0][1] = MFMA32(V1, p0, acc[0][1]); \
        acc[1][0] = MFMA32(V0, p1, acc[1][0]); \
        acc[1][1] = MFMA32(V1, p1, acc[1][1]); \
        acc[2][0] = MFMA32(V0, p2, acc[2][0]); \
        acc[2][1] = MFMA32(V1, p2, acc[2][1]); \
    } while (0)

    // wave w: j-steps s = w + 4k, k = 0..71
    const half8* qpw = qfb + (size_t)w * 64 + l;
    const half8* vpw = vfb + (size_t)w * 256 + ch * 128 + l;

    floatx4 eA[6], eB[6];
    half8 qvA = qpw[0];
    half8 v0A = vpw[0],    v1A = vpw[64];
    half8 qvB = qpw[256];
    half8 v0B = vpw[1024], v1B = vpw[1024 + 64];
    E_STEP(qvA, eA);

    for (int k = 0; k < 35; ++k) {
        const size_t s2 = (size_t)(2 * k + 2), s3 = (size_t)(2 * k + 3);
        qvA = qpw[s2 * 256];
        E_STEP(qvB, eB);
        PXV(eA, v0A, v1A);              // step 2k
        v0A = vpw[s2 * 1024]; v1A = vpw[s2 * 1024 + 64];
        qvB = qpw[s3 * 256];
        E_STEP(qvA, eA);
        PXV(eB, v0B, v1B);              // step 2k+1
        v0B = vpw[s3 * 1024]; v1B = vpw[s3 * 1024 + 64];
    }
    E_STEP(qvB, eB);
    PXV(eA, v0A, v1A);                  // step 70
    PXV(eB, v0B, v1B);                  // step 71
    #undef E_STEP
    #undef PXV

    #pragma unroll
    for (int st = 0; st < 3; ++st)
        #pragma unroll
        for (int t2 = 0; t2 < 2; ++t2)
            #pragma unroll
            for (int r = 0; r < 4; ++r)
                red[w][st][l][t2 * 4 + r] = acc[st][t2][r];
    __syncthreads();

    if (w < 3) {
        const float g = gamma[0];
        const int iq = i0 + 16 * w + (l & 15);
        #pragma unroll
        for (int t2 = 0; t2 < 2; ++t2)
            #pragma unroll
            for (int r = 0; r < 4; ++r) {
                float v = red[0][w][l][t2*4+r] + red[1][w][l][t2*4+r]
                        + red[2][w][l][t2*4+r] + red[3][w][l][t2*4+r];
                int c = 16 * (2 * ch + t2) + 4 * (l >> 4) + r;
                size_t o = ((size_t)(b * 64 + c)) * NPOS + iq;
                out[o] = g * v + x[o];
            }
    }
}

// ---------------------------------------------------------------------------
extern "C" void kernel_launch(void* const* d_in, const int* in_sizes, int n_in,
                              void* d_out, int out_size, void* d_ws, size_t ws_size,
                              hipStream_t stream)
{
    const float* x     = (const float*)d_in[0];
    const float* wq    = (const float*)d_in[1];
    const float* bq    = (const float*)d_in[2];
    const float* wk    = (const float*)d_in[3];
    const float* bk    = (const float*)d_in[4];
    const float* wv    = (const float*)d_in[5];
    const float* bv    = (const float*)d_in[6];
    const float* gamma = (const float*)d_in[7];
    float* out = (float*)d_out;

    char* wsb = (char*)d_ws;
    _Float16* Qf = (_Float16*)wsb;                       //   589,824 B
    _Float16* Kf = (_Float16*)(wsb + 589824);            //   589,824 B
    _Float16* Vf = (_Float16*)(wsb + 1179648);           // 2,359,296 B

    qkv_kernel<<<dim3(NST, BATCH), 256, 0, stream>>>(
        x, wq, bq, wk, bk, wv, bv, Qf, Kf, Vf);

    denom_kernel<<<dim3(NST, BATCH), 256, 0, stream>>>(Qf, Kf);

    attn_kernel<<<dim3(768), 256, 0, stream>>>(Qf, Kf, Vf, x, gamma, out);
}

// Round 10
// 144.337 us; speedup vs baseline: 2.6801x; 1.0032x over previous
//
#include <hip/hip_runtime.h>

using half2v  = __attribute__((ext_vector_type(2))) _Float16;
using half4   = __attribute__((ext_vector_type(4))) _Float16;
using half8   = __attribute__((ext_vector_type(8))) _Float16;
using floatx4 = __attribute__((ext_vector_type(4))) float;

constexpr int BATCH = 2;
constexpr int NPOS  = 96 * 96;    // 9216
constexpr int NT    = NPOS / 16;  // 576 sixteen-wide i-tiles
constexpr int NST   = NPOS / 32;  // 288 thirty-two-wide j-steps

#define EXP2(x) __builtin_amdgcn_exp2f(x)
#define MFMA16(A, B, C) __builtin_amdgcn_mfma_f32_16x16x16f16(A, B, C, 0, 0, 0)
#define MFMA32(A, B, C) __builtin_amdgcn_mfma_f32_16x16x32_f16(A, B, C, 0, 0, 0)

__device__ inline half8 p8_of(floatx4 e0, floatx4 e1) {
    half2v a0 = __builtin_bit_cast(half2v,
        __builtin_amdgcn_cvt_pkrtz(EXP2(e0[0]), EXP2(e0[1])));
    half2v a1 = __builtin_bit_cast(half2v,
        __builtin_amdgcn_cvt_pkrtz(EXP2(e0[2]), EXP2(e0[3])));
    half2v a2 = __builtin_bit_cast(half2v,
        __builtin_amdgcn_cvt_pkrtz(EXP2(e1[0]), EXP2(e1[1])));
    half2v a3 = __builtin_bit_cast(half2v,
        __builtin_amdgcn_cvt_pkrtz(EXP2(e1[2]), EXP2(e1[3])));
    half8 p = {a0[0], a0[1], a1[0], a1[1], a2[0], a2[1], a3[0], a3[1]};
    return p;
}

// ---------------------------------------------------------------------------
// K1: QKV projection (R8 body, padded LDS).
// Qf: j-permuted A-layout, log2e-scaled, d>=8 zeroed (denom runs pre-patch).
// Kf: B-layout, d=8,9 = 1.0 (augment channels). Vf: K=32 A-layout f16.
// ---------------------------------------------------------------------------
__global__ __launch_bounds__(256) void qkv_kernel(
    const float* __restrict__ x,
    const float* __restrict__ wq, const float* __restrict__ bq,
    const float* __restrict__ wk, const float* __restrict__ bk,
    const float* __restrict__ wv, const float* __restrict__ bv,
    _Float16* __restrict__ Qf, _Float16* __restrict__ Kf,
    _Float16* __restrict__ Vf)
{
    __shared__ float W[80][64];
    __shared__ float bias[80];
    __shared__ float qs[32][9];
    __shared__ float ks[32][9];
    __shared__ _Float16 vs[32][72];
    const int tid = threadIdx.x;
    for (int idx = tid; idx < 80 * 64; idx += 256) {
        int o = idx >> 6, c = idx & 63;
        float w;
        if (o < 8)       w = wq[o * 64 + c];
        else if (o < 16) w = wk[(o - 8) * 64 + c];
        else             w = wv[(o - 16) * 64 + c];
        W[o][c] = w;
    }
    if (tid < 80) {
        float bb;
        if (tid < 8)       bb = bq[tid];
        else if (tid < 16) bb = bk[tid - 8];
        else               bb = bv[tid - 16];
        bias[tid] = bb;
    }
    __syncthreads();

    const int js = blockIdx.x;          // 0..287
    const int b  = blockIdx.y;
    const int part = tid >> 5;          // 0..7
    const int jl   = tid & 31;
    const int i    = js * 32 + jl;

    float xr[64];
    #pragma unroll
    for (int c = 0; c < 64; ++c)
        xr[c] = x[(size_t)(b * 64 + c) * NPOS + i];

    #pragma unroll
    for (int q = 0; q < 10; ++q) {
        const int o = part * 10 + q;
        float s = bias[o];
        #pragma unroll
        for (int c4 = 0; c4 < 16; ++c4) {
            float4 w4 = *(const float4*)&W[o][c4 * 4];
            s += w4.x * xr[c4*4+0] + w4.y * xr[c4*4+1]
               + w4.z * xr[c4*4+2] + w4.w * xr[c4*4+3];
        }
        if (o < 8)       qs[jl][o] = s;
        else if (o < 16) ks[jl][o - 8] = s;
        else             vs[jl][o - 16] = (_Float16)s;
    }
    __syncthreads();

    const size_t tile = (size_t)b * NST + js;
    {   // Vf
        const int ct = tid >> 6, l = tid & 63;
        const int g = l >> 4, cl = l & 15;
        half8 o8;
        #pragma unroll
        for (int idx = 0; idx < 8; ++idx)
            o8[idx] = vs[8 * g + idx][16 * ct + cl];
        *(half8*)&Vf[(tile * 256 + ct * 64 + l) * 8] = o8;
    }
    if (tid < 128) {   // Qf (j-permuted, log2e-scaled)
        const int l = tid >> 1, e = tid & 1;
        const int m = l & 15, g = l >> 4;
        const int jsrc = 8 * (m >> 2) + 4 * e + (m & 3);
        constexpr float LOG2E = 1.44269504088896f;
        half4 qh;
        #pragma unroll
        for (int r = 0; r < 4; ++r)
            qh[r] = (g < 2) ? (_Float16)(qs[jsrc][4 * g + r] * LOG2E)
                            : (_Float16)0.f;
        ((half4*)Qf)[(tile * 64 + l) * 2 + e] = qh;
    } else {           // Kf (augment dims d=8,9 -> 1.0)
        const int t = tid - 128;
        const int ht = t >> 6, l = t & 63;
        const int il = l & 15, g = l >> 4;
        const int it = js * 2 + ht;
        half4 kh;
        #pragma unroll
        for (int r = 0; r < 4; ++r) {
            if (g < 2)       kh[r] = (_Float16)ks[16 * ht + il][4 * g + r];
            else if (g == 2) kh[r] = (r < 2) ? (_Float16)1.f : (_Float16)0.f;
            else             kh[r] = (_Float16)0.f;
        }
        ((half4*)Kf)[(size_t)(b * NT + it) * 64 + l] = kh;
    }
}

// ---------------------------------------------------------------------------
// K2: denom + patch fused (R8 body, cleaned). Block = ONE 32-j tile x full i.
// ---------------------------------------------------------------------------
__global__ __launch_bounds__(256, 4) void denom_kernel(
    _Float16* __restrict__ Qf, const _Float16* __restrict__ Kf)
{
    __shared__ float LpS[4][32];
    const int tid = threadIdx.x;
    const int w = tid >> 6, l = tid & 63;
    const int js = blockIdx.x;          // 0..287
    const int b  = blockIdx.y;
    const size_t tile = (size_t)b * NST + js;
    const half8* __restrict__ qfb = (const half8*)Qf + (size_t)b * NST * 64;
    const half4* __restrict__ kfb = (const half4*)Kf + (size_t)b * NT * 64;

    half8 qv = qfb[(size_t)js * 64 + l];
    half4 q0 = __builtin_shufflevector(qv, qv, 0, 1, 2, 3);
    half4 q1 = __builtin_shufflevector(qv, qv, 4, 5, 6, 7);

    float sum[2][4];
    #pragma unroll
    for (int e = 0; e < 2; ++e)
        #pragma unroll
        for (int r = 0; r < 4; ++r) sum[e][r] = 0.f;

    const floatx4 z = {0.f, 0.f, 0.f, 0.f};
    #define DACC(E0, E1) do { \
        _Pragma("unroll") \
        for (int r = 0; r < 4; ++r) { \
            sum[0][r] += EXP2(E0[r]); sum[1][r] += EXP2(E1[r]); } \
    } while (0)

    const half4* kp = kfb + (size_t)w * 64 + l;
    half4 kfA = kp[0];
    half4 kfB = kp[256];
    floatx4 eA0 = MFMA16(q0, kfA, z), eA1 = MFMA16(q1, kfA, z);
    floatx4 eB0, eB1;
    for (int k = 0; k < 71; ++k) {
        kfA = kp[(size_t)(2 * k + 2) * 256];
        eB0 = MFMA16(q0, kfB, z); eB1 = MFMA16(q1, kfB, z);
        DACC(eA0, eA1);
        kfB = kp[(size_t)(2 * k + 3) * 256];
        eA0 = MFMA16(q0, kfA, z); eA1 = MFMA16(q1, kfA, z);
        DACC(eB0, eB1);
    }
    eB0 = MFMA16(q0, kfB, z); eB1 = MFMA16(q1, kfB, z);
    DACC(eA0, eA1);
    DACC(eB0, eB1);
    #undef DACC

    #pragma unroll
    for (int e = 0; e < 2; ++e)
        #pragma unroll
        for (int r = 0; r < 4; ++r)
            #pragma unroll
            for (int m = 1; m < 16; m <<= 1)
                sum[e][r] += __shfl_xor(sum[e][r], m, 64);

    if ((l & 15) == 0) {
        const int g = l >> 4;
        #pragma unroll
        for (int e = 0; e < 2; ++e)
            #pragma unroll
            for (int r = 0; r < 4; ++r)
                LpS[w][8 * g + 4 * e + r] = sum[e][r];
    }
    __syncthreads();

    if (tid < 32) {
        const float L = LpS[0][tid] + LpS[1][tid] + LpS[2][tid] + LpS[3][tid];
        const float v = -__log2f(L);
        _Float16 hi = (_Float16)v;
        _Float16 lo = (_Float16)(v - (float)hi);
        const int m = 4 * (tid >> 3) + (tid & 3);
        const int e = (tid >> 2) & 1;
        half2v hl = {hi, lo};
        ((half2v*)Qf)[((tile * 64 + m + 32) * 2 + e) * 2] = hl;
    }
}

// ---------------------------------------------------------------------------
// K3: attention, direct-out, ONE exp per (i,j). Grid 384: block = 48 i
// (3 subtiles) x FULL 64 c x full j; waves = j-quarters (72 steps of 32 j).
// Per step: 6 E-MFMA + 24 exp + 12 pkrtz + 12 PV-MFMA(16x16x32, 4 c-tiles).
// Depth-1 q/v prefetch. Epilogue: 4-shard LDS combine, out = gamma*acc + x.
// ---------------------------------------------------------------------------
__global__ __launch_bounds__(256, 2) void attn_kernel(
    const _Float16* __restrict__ Qf, const _Float16* __restrict__ Kf,
    const _Float16* __restrict__ Vf,
    const float* __restrict__ x, const float* __restrict__ gamma,
    float* __restrict__ out)
{
    __shared__ float red[4][3][64][17];   // 52.2 KB
    const int s = blockIdx.x;            // 0..383
    const int b   = s & 1;
    const int igl = s >> 1;              // 0..191
    const int tid = threadIdx.x;
    const int w = tid >> 6, l = tid & 63;
    const int it0 = igl * 3, i0 = igl * 48;

    const half8* __restrict__ qfb = (const half8*)Qf + (size_t)b * NST * 64;
    const half4* __restrict__ kfb = (const half4*)Kf + (size_t)b * NT * 64;
    const half8* __restrict__ vfb = (const half8*)Vf + (size_t)b * NST * 256;

    half4 kf[3];
    #pragma unroll
    for (int st = 0; st < 3; ++st) kf[st] = kfb[(size_t)(it0 + st) * 64 + l];

    floatx4 acc[3][4];
    #pragma unroll
    for (int st = 0; st < 3; ++st)
        #pragma unroll
        for (int ct = 0; ct < 4; ++ct)
            acc[st][ct] = (floatx4){0.f, 0.f, 0.f, 0.f};

    const floatx4 z = {0.f, 0.f, 0.f, 0.f};

    #define ASTEP(QV, V0, V1, V2, V3) do { \
        half4 qe0 = __builtin_shufflevector(QV, QV, 0, 1, 2, 3); \
        half4 qe1 = __builtin_shufflevector(QV, QV, 4, 5, 6, 7); \
        _Pragma("unroll") \
        for (int st = 0; st < 3; ++st) { \
            floatx4 e0 = MFMA16(qe0, kf[st], z); \
            floatx4 e1 = MFMA16(qe1, kf[st], z); \
            half8 p = p8_of(e0, e1); \
            acc[st][0] = MFMA32(V0, p, acc[st][0]); \
            acc[st][1] = MFMA32(V1, p, acc[st][1]); \
            acc[st][2] = MFMA32(V2, p, acc[st][2]); \
            acc[st][3] = MFMA32(V3, p, acc[st][3]); \
        } \
    } while (0)

    // wave w: j-steps w + 4k, k = 0..71
    const half8* qpw = qfb + (size_t)w * 64 + l;
    const half8* vpw = vfb + (size_t)w * 256 + l;

    half8 qv = qpw[0];
    half8 v0 = vpw[0], v1 = vpw[64], v2 = vpw[128], v3 = vpw[192];
    for (int k = 0; k < 71; ++k) {
        const size_t nx = (size_t)(k + 1);
        half8 qn  = qpw[nx * 256];
        half8 v0n = vpw[nx * 1024],       v1n = vpw[nx * 1024 + 64];
        half8 v2n = vpw[nx * 1024 + 128], v3n = vpw[nx * 1024 + 192];
        ASTEP(qv, v0, v1, v2, v3);
        qv = qn; v0 = v0n; v1 = v1n; v2 = v2n; v3 = v3n;
    }
    ASTEP(qv, v0, v1, v2, v3);
    #undef ASTEP

    #pragma unroll
    for (int st = 0; st < 3; ++st)
        #pragma unroll
        for (int ct = 0; ct < 4; ++ct)
            #pragma unroll
            for (int r = 0; r < 4; ++r)
                red[w][st][l][ct * 4 + r] = acc[st][ct][r];
    __syncthreads();

    if (w < 3) {
        const float g = gamma[0];
        const int iq = i0 + 16 * w + (l & 15);
        #pragma unroll
        for (int ct = 0; ct < 4; ++ct)
            #pragma unroll
            for (int r = 0; r < 4; ++r) {
                float v = red[0][w][l][ct*4+r] + red[1][w][l][ct*4+r]
                        + red[2][w][l][ct*4+r] + red[3][w][l][ct*4+r];
                int c = 16 * ct + 4 * (l >> 4) + r;
                size_t o = ((size_t)(b * 64 + c)) * NPOS + iq;
                out[o] = g * v + x[o];
            }
    }
}

// ---------------------------------------------------------------------------
extern "C" void kernel_launch(void* const* d_in, const int* in_sizes, int n_in,
                              void* d_out, int out_size, void* d_ws, size_t ws_size,
                              hipStream_t stream)
{
    const float* x     = (const float*)d_in[0];
    const float* wq    = (const float*)d_in[1];
    const float* bq    = (const float*)d_in[2];
    const float* wk    = (const float*)d_in[3];
    const float* bk    = (const float*)d_in[4];
    const float* wv    = (const float*)d_in[5];
    const float* bv    = (const float*)d_in[6];
    const float* gamma = (const float*)d_in[7];
    float* out = (float*)d_out;

    char* wsb = (char*)d_ws;
    _Float16* Qf = (_Float16*)wsb;                       //   589,824 B
    _Float16* Kf = (_Float16*)(wsb + 589824);            //   589,824 B
    _Float16* Vf = (_Float16*)(wsb + 1179648);           // 2,359,296 B

    qkv_kernel<<<dim3(NST, BATCH), 256, 0, stream>>>(
        x, wq, bq, wk, bk, wv, bv, Qf, Kf, Vf);

    denom_kernel<<<dim3(NST, BATCH), 256, 0, stream>>>(Qf, Kf);

    attn_kernel<<<dim3(384), 256, 0, stream>>>(Qf, Kf, Vf, x, gamma, out);
}